// Round 12
// baseline (680.885 us; speedup 1.0000x reference)
//
#include <hip/hip_runtime.h>
#include <hip/hip_fp16.h>
#include <math.h>

#define NN 50000
#define NH 50000
#define NI 800000
#define NL 20000

// All activation tables are column-blocked ("sliced"):
//   node tables [50000][128] fp16 -> 8 slices of 16 cols; slice stride 800000 halfs (3.2MB)
//   edge tables [50000][64]  fp16 -> 8 slices of  8 cols; slice stride 400000 halfs (0.8MB)
// Pull kernels pin slice = blockIdx&7 so each XCD gathers within an L2-resident slice.

using half8 = __attribute__((ext_vector_type(8))) _Float16;
using f32x4 = __attribute__((ext_vector_type(4))) float;

// ================= helpers =================
static __device__ __forceinline__ float2 pack_h4(float4 v) {
    float2 st;
    *(__half2*)&st.x = __float22half2_rn(make_float2(v.x, v.y));
    *(__half2*)&st.y = __float22half2_rn(make_float2(v.z, v.w));
    return st;
}
static __device__ __forceinline__ void acc_h8(float4& a, float4& b, float4 raw) {
    const __half2* hp = (const __half2*)&raw;
    float2 f0 = __half22float2(hp[0]);
    float2 f1 = __half22float2(hp[1]);
    float2 f2 = __half22float2(hp[2]);
    float2 f3 = __half22float2(hp[3]);
    a.x += f0.x; a.y += f0.y; a.z += f1.x; a.w += f1.y;
    b.x += f2.x; b.y += f2.y; b.z += f3.x; b.w += f3.y;
}
static __device__ __forceinline__ float4 pack_h8(float4 a, float4 b) {
    float4 st;
    ((__half2*)&st)[0] = __float22half2_rn(make_float2(a.x, a.y));
    ((__half2*)&st)[1] = __float22half2_rn(make_float2(a.z, a.w));
    ((__half2*)&st)[2] = __float22half2_rn(make_float2(b.x, b.y));
    ((__half2*)&st)[3] = __float22half2_rn(make_float2(b.z, b.w));
    return st;
}

// ================= prep: 7 weight transposes + XCD-bucketed histogram ==========
#define WT_BLKS 1088
#define HIST_SEGS 98
#define HIST_PER  8164
__global__ void k_prep(const float* __restrict__ Wn0, const float* __restrict__ Wn1,
                       const float* __restrict__ Wn2, const float* __restrict__ We0,
                       const float* __restrict__ We1, const float* __restrict__ We2,
                       const float* __restrict__ W1,
                       __half* __restrict__ Wnt0, __half* __restrict__ Wnt1,
                       __half* __restrict__ Wnt2, __half* __restrict__ Wet0,
                       __half* __restrict__ Wet1, __half* __restrict__ Wet2,
                       __half* __restrict__ W1t,
                       const int* __restrict__ ei, int* __restrict__ cnt_n,
                       int* __restrict__ cnt_h) {
    int b = blockIdx.x, t = threadIdx.x;
    if (b < WT_BLKS) {
        int u = b * 256 + t;
        if (u < 278528) {
            const float* S; __half* D; int K, N;
            if (u < 32768)      { S = Wn0; D = Wnt0; K = 256; N = 128; }
            else if (u < 49152) { S = Wn1; D = Wnt1; K = 128; N = 128; u -= 32768; }
            else if (u < 65536) { S = Wn2; D = Wnt2; K = 128; N = 128; u -= 49152; }
            else if (u < 73728) { S = We0; D = Wet0; K = 128; N = 64;  u -= 65536; }
            else if (u < 77824) { S = We1; D = Wet1; K = 64;  N = 64;  u -= 73728; }
            else if (u < 81920) { S = We2; D = Wet2; K = 64;  N = 64;  u -= 77824; }
            else                { S = W1;  D = W1t;  K = 768; N = 256; u -= 81920; }
            int n = u / K, k = u % K;
            D[(size_t)n * K + k] = __float2half(S[(size_t)k * N + n]);
        }
    } else {
        int hb = b - WT_BLKS;
        int bucket = hb & 7;
        int seg = hb >> 3;
        int lo = seg * HIST_PER;
        int hi = min(lo + HIST_PER, NI);
        for (int e = lo + t; e < hi; e += 256) {
            int s = ei[e], d = ei[e + NI];
            if (s / 6250 == bucket) atomicAdd(&cnt_n[s], 1);
            if (d / 6250 == bucket) atomicAdd(&cnt_h[d], 1);
        }
    }
}

// ================= 3-phase multi-block scan =================
__global__ void k_scanp1(const int* __restrict__ cnt_n, const int* __restrict__ cnt_h,
                         int* __restrict__ parts) {
    __shared__ int s[256];
    int arr = blockIdx.x / 196, blk = blockIdx.x % 196, t = threadIdx.x;
    const int* cnt = arr ? cnt_h : cnt_n;
    int i = blk * 256 + t;
    int v = (i < 50000) ? cnt[i] : 0;
    s[t] = v;
    __syncthreads();
#pragma unroll
    for (int d = 128; d > 0; d >>= 1) {
        if (t < d) s[t] += s[t + d];
        __syncthreads();
    }
    if (t == 0) parts[arr * 256 + blk] = s[0];
}

__global__ void k_scanp2(int* __restrict__ parts, int* __restrict__ off_n,
                         int* __restrict__ off_h) {
    __shared__ int s[256];
    int b = blockIdx.x, t = threadIdx.x;
    int* P = parts + b * 256;
    int v = (t < 196) ? P[t] : 0;
    s[t] = v;
    __syncthreads();
#pragma unroll
    for (int d = 1; d < 256; d <<= 1) {
        int u = (t >= d) ? s[t - d] : 0;
        __syncthreads();
        s[t] += u;
        __syncthreads();
    }
    if (t < 196) P[t] = s[t] - v;          // exclusive
    if (t == 0) {
        int* off = b ? off_h : off_n;
        off[50000] = s[255];
    }
}

__global__ void k_scanp3(const int* __restrict__ cnt_n, const int* __restrict__ cnt_h,
                         const int* __restrict__ parts, int* __restrict__ off_n,
                         int* __restrict__ off_h, float* __restrict__ invn,
                         float* __restrict__ invh) {
    __shared__ int s[256];
    int arr = blockIdx.x / 196, blk = blockIdx.x % 196, t = threadIdx.x;
    const int* cnt = arr ? cnt_h : cnt_n;
    int* off = arr ? off_h : off_n;
    float* inv = arr ? invh : invn;
    int i = blk * 256 + t;
    int c = (i < 50000) ? cnt[i] : 0;
    s[t] = c;
    __syncthreads();
#pragma unroll
    for (int d = 1; d < 256; d <<= 1) {
        int u = (t >= d) ? s[t - d] : 0;
        __syncthreads();
        s[t] += u;
        __syncthreads();
    }
    if (i < 50000) {
        off[i] = parts[arr * 256 + blk] + s[t] - c;
        inv[i] = c > 0 ? 1.0f / (float)c : 0.0f;
    }
}

// ================= XCD-bucketed CSR fill =================
#define FILL_SEGS 98
#define FILL_PER  8164
__global__ void k_fill(const int* __restrict__ ei, const int* __restrict__ off_n,
                       const int* __restrict__ off_h, int* __restrict__ cur_n,
                       int* __restrict__ cur_h, int* __restrict__ adj_n,
                       int* __restrict__ adj_h) {
    int bucket = blockIdx.x & 7;
    int seg = blockIdx.x >> 3;
    int lo = seg * FILL_PER;
    int hi = min(lo + FILL_PER, NI);
    for (int e = lo + (int)threadIdx.x; e < hi; e += 256) {
        int s = ei[e], d = ei[e + NI];
        if (d / 6250 == bucket) {
            int p = atomicAdd(&cur_h[d], 1);
            adj_h[off_h[d] + p] = s;
        }
        if (s / 6250 == bucket) {
            int q = atomicAdd(&cur_n[s], 1);
            adj_n[off_n[s] + q] = d;
        }
    }
}

// ================= MFMA GEMM body; sliced C-write, sliced half A-read ==========
// SC = slice width of the OUTPUT table (16 node / 8 edge). Input X: fp32 row-major
// (layer 0) or fp16 sliced with width SCI (16 node / 8 edge chains).
template <typename SrcT, int BM, int BN, int FM, int FN, int SCI>
static __device__ __forceinline__ void gemm_body(const SrcT* __restrict__ X,
                                                 const __half* __restrict__ Wt,
                                                 __half* __restrict__ Y, int M, int K,
                                                 int blk, __half* smem) {
    constexpr int LDK = 56;
    constexpr int WN = BN / 4;
    __half* Xs = smem;
    __half* Ws = smem + BM * LDK;
    int t = threadIdx.x;
    int wave = t >> 6, lane = t & 63;
    int g = lane >> 4, lr = lane & 15;
    int bm0 = blk * BM;
    f32x4 acc[FM][FN] = {};

    for (int k0 = 0; k0 < K; k0 += 32) {
        for (int u = t; u < BM * 4; u += 256) {
            int r = u >> 2, q = u & 3;
            int rg = bm0 + r; if (rg >= M) rg = M - 1;
            if constexpr (sizeof(SrcT) == 4) {
                const float* src = (const float*)X + (size_t)rg * K + k0 + q * 8;
                float4 v0 = *(const float4*)src;
                float4 v1 = *(const float4*)(src + 4);
                *(float2*)&Xs[r * LDK + q * 8]     = pack_h4(v0);
                *(float2*)&Xs[r * LDK + q * 8 + 4] = pack_h4(v1);
            } else if constexpr (SCI == 16) {
                int kk0 = k0 + q * 8;
                const __half* src = (const __half*)X +
                    (size_t)(kk0 >> 4) * ((size_t)M * 16) + (size_t)rg * 16 + (kk0 & 15);
                *(float4*)&Xs[r * LDK + q * 8] = *(const float4*)src;
            } else {
                const __half* src = (const __half*)X +
                    (size_t)((k0 >> 3) + q) * ((size_t)M * 8) + (size_t)rg * 8;
                *(float4*)&Xs[r * LDK + q * 8] = *(const float4*)src;
            }
        }
        for (int u = t; u < BN * 4; u += 256) {
            int r = u >> 2, q = u & 3;
            *(float4*)&Ws[r * LDK + q * 8] = *(const float4*)&Wt[(size_t)r * K + k0 + q * 8];
        }
        __syncthreads();
        half8 a[FM], b[FN];
#pragma unroll
        for (int fm = 0; fm < FM; fm++)
            a[fm] = *(const half8*)&Xs[(fm * 16 + lr) * LDK + g * 8];
#pragma unroll
        for (int fn = 0; fn < FN; fn++)
            b[fn] = *(const half8*)&Ws[(wave * WN + fn * 16 + lr) * LDK + g * 8];
#pragma unroll
        for (int fm = 0; fm < FM; fm++)
#pragma unroll
            for (int fn = 0; fn < FN; fn++)
                acc[fm][fn] = __builtin_amdgcn_mfma_f32_16x16x32_f16(a[fm], b[fn], acc[fm][fn], 0, 0, 0);
        __syncthreads();
    }
    // sliced C-write (coalesced: 16 lanes x 2B contiguous per (g,reg))
#pragma unroll
    for (int fm = 0; fm < FM; fm++) {
#pragma unroll
        for (int fn = 0; fn < FN; fn++) {
            __half* dst;
            int col;
            if constexpr (BN == 128) {
                dst = Y + (size_t)(wave * 2 + fn) * ((size_t)M * 16);
                col = lr;
#pragma unroll
                for (int reg = 0; reg < 4; reg++) {
                    int rg = bm0 + fm * 16 + g * 4 + reg;
                    if (rg < M) dst[(size_t)rg * 16 + col] = __float2half(acc[fm][fn][reg]);
                }
            } else {
                dst = Y + (size_t)(wave * 2 + (lr >> 3)) * ((size_t)M * 8);
                col = lr & 7;
#pragma unroll
                for (int reg = 0; reg < 4; reg++) {
                    int rg = bm0 + fm * 16 + g * 4 + reg;
                    if (rg < M) dst[(size_t)rg * 8 + col] = __float2half(acc[fm][fn][reg]);
                }
            }
        }
    }
}

template <typename SrcT>
__global__ void __launch_bounds__(256)
k_gemm2(const SrcT* __restrict__ Xn, const __half* __restrict__ Wtn,
        __half* __restrict__ Yn, int Kn,
        const SrcT* __restrict__ Xe, const __half* __restrict__ Wte,
        __half* __restrict__ Ye, int Ke) {
    __shared__ __align__(16) __half smem[(64 + 128) * 56];
    if (blockIdx.x < 782)
        gemm_body<SrcT, 64, 128, 4, 2, 16>(Xn, Wtn, Yn, NN, Kn, blockIdx.x, smem);
    else
        gemm_body<SrcT, 64, 64, 4, 1, 8>(Xe, Wte, Ye, NH, Ke, blockIdx.x - 782, smem);
}

// ================= sliced pull: slice = blockIdx&7 pins each slice to one XCD ===
// node side: slice = 16 cols (32B/row, 2 lanes/row, 128 rows/block), 391 blocks/slice
// edge side: slice =  8 cols (16B/row, 1 lane/row, 256 rows/block), 196 blocks/slice
#define PULL_RB_A 391
#define PULL_RB_B 196
template <bool RELU>
__global__ void __launch_bounds__(256)
k_pull2(const __half* __restrict__ inA, const int* __restrict__ offA,
        const int* __restrict__ adjA, const float* __restrict__ scA,
        const float* __restrict__ biA, __half* __restrict__ outA,
        const __half* __restrict__ inB, const int* __restrict__ offB,
        const int* __restrict__ adjB, const float* __restrict__ scB,
        const float* __restrict__ biB, __half* __restrict__ outB) {
    int s = blockIdx.x & 7;
    int rb = blockIdx.x >> 3;
    int t = threadIdx.x;
    float4 a0 = {0,0,0,0}, b0 = {0,0,0,0}, a1 = {0,0,0,0}, b1v = {0,0,0,0};
    float4 a2 = {0,0,0,0}, b2v = {0,0,0,0}, a3 = {0,0,0,0}, b3 = {0,0,0,0};
    if (rb < PULL_RB_A) {
        int r = rb * 128 + (t >> 1);
        int L = t & 1;
        if (r >= 50000) return;
        const float4* src4 = (const float4*)inA + (size_t)s * 100000 + L;
        int lo = offA[r], hi = offA[r + 1];
        int j = lo;
        for (; j + 7 < hi; j += 8) {
            int c0 = adjA[j], c1 = adjA[j+1], c2 = adjA[j+2], c3 = adjA[j+3];
            int c4 = adjA[j+4], c5 = adjA[j+5], c6 = adjA[j+6], c7 = adjA[j+7];
            float4 v0 = src4[(size_t)c0 * 2];
            float4 v1 = src4[(size_t)c1 * 2];
            float4 v2 = src4[(size_t)c2 * 2];
            float4 v3 = src4[(size_t)c3 * 2];
            float4 v4 = src4[(size_t)c4 * 2];
            float4 v5 = src4[(size_t)c5 * 2];
            float4 v6 = src4[(size_t)c6 * 2];
            float4 v7 = src4[(size_t)c7 * 2];
            acc_h8(a0, b0, v0); acc_h8(a1, b1v, v1); acc_h8(a2, b2v, v2); acc_h8(a3, b3, v3);
            acc_h8(a0, b0, v4); acc_h8(a1, b1v, v5); acc_h8(a2, b2v, v6); acc_h8(a3, b3, v7);
        }
        for (; j < hi; j++) {
            float4 v0 = src4[(size_t)adjA[j] * 2];
            acc_h8(a0, b0, v0);
        }
        a0.x += a1.x + a2.x + a3.x; a0.y += a1.y + a2.y + a3.y;
        a0.z += a1.z + a2.z + a3.z; a0.w += a1.w + a2.w + a3.w;
        b0.x += b1v.x + b2v.x + b3.x; b0.y += b1v.y + b2v.y + b3.y;
        b0.z += b1v.z + b2v.z + b3.z; b0.w += b1v.w + b2v.w + b3.w;
        float sc = scA[r];
        if (RELU) {
            float4 ba = *(const float4*)&biA[s * 16 + L * 8];
            float4 bb = *(const float4*)&biA[s * 16 + L * 8 + 4];
            a0.x = fmaxf(fmaf(a0.x, sc, ba.x), 0.f);
            a0.y = fmaxf(fmaf(a0.y, sc, ba.y), 0.f);
            a0.z = fmaxf(fmaf(a0.z, sc, ba.z), 0.f);
            a0.w = fmaxf(fmaf(a0.w, sc, ba.w), 0.f);
            b0.x = fmaxf(fmaf(b0.x, sc, bb.x), 0.f);
            b0.y = fmaxf(fmaf(b0.y, sc, bb.y), 0.f);
            b0.z = fmaxf(fmaf(b0.z, sc, bb.z), 0.f);
            b0.w = fmaxf(fmaf(b0.w, sc, bb.w), 0.f);
        } else {
            a0.x *= sc; a0.y *= sc; a0.z *= sc; a0.w *= sc;
            b0.x *= sc; b0.y *= sc; b0.z *= sc; b0.w *= sc;
        }
        ((float4*)outA)[(size_t)s * 100000 + (size_t)r * 2 + L] = pack_h8(a0, b0);
    } else {
        int r = (rb - PULL_RB_A) * 256 + t;
        if (r >= 50000) return;
        const float4* src4 = (const float4*)inB + (size_t)s * 50000;
        int lo = offB[r], hi = offB[r + 1];
        int j = lo;
        for (; j + 7 < hi; j += 8) {
            int c0 = adjB[j], c1 = adjB[j+1], c2 = adjB[j+2], c3 = adjB[j+3];
            int c4 = adjB[j+4], c5 = adjB[j+5], c6 = adjB[j+6], c7 = adjB[j+7];
            float4 v0 = src4[c0];
            float4 v1 = src4[c1];
            float4 v2 = src4[c2];
            float4 v3 = src4[c3];
            float4 v4 = src4[c4];
            float4 v5 = src4[c5];
            float4 v6 = src4[c6];
            float4 v7 = src4[c7];
            acc_h8(a0, b0, v0); acc_h8(a1, b1v, v1); acc_h8(a2, b2v, v2); acc_h8(a3, b3, v3);
            acc_h8(a0, b0, v4); acc_h8(a1, b1v, v5); acc_h8(a2, b2v, v6); acc_h8(a3, b3, v7);
        }
        for (; j < hi; j++) {
            float4 v0 = src4[adjB[j]];
            acc_h8(a0, b0, v0);
        }
        a0.x += a1.x + a2.x + a3.x; a0.y += a1.y + a2.y + a3.y;
        a0.z += a1.z + a2.z + a3.z; a0.w += a1.w + a2.w + a3.w;
        b0.x += b1v.x + b2v.x + b3.x; b0.y += b1v.y + b2v.y + b3.y;
        b0.z += b1v.z + b2v.z + b3.z; b0.w += b1v.w + b2v.w + b3.w;
        float sc = scB[r];
        if (RELU) {
            float4 ba = *(const float4*)&biB[s * 8];
            float4 bb = *(const float4*)&biB[s * 8 + 4];
            a0.x = fmaxf(fmaf(a0.x, sc, ba.x), 0.f);
            a0.y = fmaxf(fmaf(a0.y, sc, ba.y), 0.f);
            a0.z = fmaxf(fmaf(a0.z, sc, ba.z), 0.f);
            a0.w = fmaxf(fmaf(a0.w, sc, ba.w), 0.f);
            b0.x = fmaxf(fmaf(b0.x, sc, bb.x), 0.f);
            b0.y = fmaxf(fmaf(b0.y, sc, bb.y), 0.f);
            b0.z = fmaxf(fmaf(b0.z, sc, bb.z), 0.f);
            b0.w = fmaxf(fmaf(b0.w, sc, bb.w), 0.f);
        } else {
            a0.x *= sc; a0.y *= sc; a0.z *= sc; a0.w *= sc;
            b0.x *= sc; b0.y *= sc; b0.z *= sc; b0.w *= sc;
        }
        ((float4*)outB)[(size_t)s * 50000 + r] = pack_h8(a0, b0);
    }
}
#define PULL_GRID (8 * (PULL_RB_A + PULL_RB_B))

// ================= fused final MLP via MFMA (sliced feature gathers) ===========
__global__ void __launch_bounds__(256)
k_mlp_mfma(const __half* __restrict__ hx1, const __half* __restrict__ hx2,
           const __half* __restrict__ hx3, const __half* __restrict__ gx1,
           const __half* __restrict__ gx2, const __half* __restrict__ gx3,
           const int* __restrict__ marks, const int* __restrict__ emarks,
           const __half* __restrict__ W1t, const float* __restrict__ b1,
           const float* __restrict__ W2, const float* __restrict__ b2,
           float* __restrict__ out) {
    constexpr int LDK = 56;
    __shared__ __align__(16) __half Xs[32 * LDK];
    __shared__ __align__(16) __half Ws[256 * LDK];
    __shared__ float part[4][32][2];
    int t = threadIdx.x;
    int wave = t >> 6, lane = t & 63;
    int g = lane >> 4, lr = lane & 15;
    int bm0 = blockIdx.x * 32;
    int r_s = t >> 2, q_s = t & 3;
    int m_s = 0, e_s = 0;
    if (t < 128) {
        int l = bm0 + r_s; if (l >= NL) l = NL - 1;
        m_s = marks[l]; e_s = emarks[l];
    }
    f32x4 acc[2][4] = {};

    for (int k0 = 0; k0 < 768; k0 += 32) {
        if (t < 128) {
            if (k0 < 384) {
                int fb = (k0 < 192 ? k0 : k0 - 192) + q_s * 8;
                const __half* gs = fb < 64 ? gx1 : (fb < 128 ? gx2 : gx3);
                int off = fb & 63;
                const __half* base = gs + (size_t)(off >> 3) * 400000;
                half8 va = *(const half8*)&base[(size_t)e_s * 8];
                half8 vb = *(const half8*)&base[(size_t)(e_s + 1) * 8];
                half8 rv;
                if (k0 < 192) {
#pragma unroll
                    for (int j = 0; j < 8; j++)
                        rv[j] = (_Float16)fminf((float)va[j], (float)vb[j]);
                } else {
#pragma unroll
                    for (int j = 0; j < 8; j++)
                        rv[j] = (_Float16)fmaxf((float)va[j], (float)vb[j]);
                }
                *(half8*)&Xs[r_s * LDK + q_s * 8] = rv;
            } else {
                int fb = (k0 - 384) + q_s * 8;
                const __half* hs = fb < 128 ? hx1 : (fb < 256 ? hx2 : hx3);
                int off = fb & 127;
                const __half* base = hs + (size_t)(off >> 4) * 800000;
                *(float4*)&Xs[r_s * LDK + q_s * 8] =
                    *(const float4*)&base[(size_t)m_s * 16 + (off & 15)];
            }
        }
        for (int u = t; u < 1024; u += 256) {
            int r = u >> 2, q = u & 3;
            *(float4*)&Ws[r * LDK + q * 8] = *(const float4*)&W1t[(size_t)r * 768 + k0 + q * 8];
        }
        __syncthreads();
        half8 a[2], b[4];
#pragma unroll
        for (int fm = 0; fm < 2; fm++)
            a[fm] = *(const half8*)&Xs[(fm * 16 + lr) * LDK + g * 8];
#pragma unroll
        for (int fn = 0; fn < 4; fn++)
            b[fn] = *(const half8*)&Ws[(wave * 64 + fn * 16 + lr) * LDK + g * 8];
#pragma unroll
        for (int fm = 0; fm < 2; fm++)
#pragma unroll
            for (int fn = 0; fn < 4; fn++)
                acc[fm][fn] = __builtin_amdgcn_mfma_f32_16x16x32_f16(a[fm], b[fn], acc[fm][fn], 0, 0, 0);
        __syncthreads();
    }
    float b1c[4], w20[4], w21[4];
#pragma unroll
    for (int fn = 0; fn < 4; fn++) {
        int col = wave * 64 + fn * 16 + lr;
        b1c[fn] = b1[col];
        w20[fn] = W2[(size_t)col * 2 + 0];
        w21[fn] = W2[(size_t)col * 2 + 1];
    }
    float p0[2][4], p1[2][4];
#pragma unroll
    for (int fm = 0; fm < 2; fm++) {
#pragma unroll
        for (int reg = 0; reg < 4; reg++) {
            float s0 = 0.f, s1 = 0.f;
#pragma unroll
            for (int fn = 0; fn < 4; fn++) {
                float hh = fmaxf(acc[fm][fn][reg] + b1c[fn], 0.f);
                s0 = fmaf(hh, w20[fn], s0);
                s1 = fmaf(hh, w21[fn], s1);
            }
            p0[fm][reg] = s0; p1[fm][reg] = s1;
        }
    }
#pragma unroll
    for (int mask = 1; mask < 16; mask <<= 1) {
#pragma unroll
        for (int fm = 0; fm < 2; fm++)
#pragma unroll
            for (int reg = 0; reg < 4; reg++) {
                p0[fm][reg] += __shfl_xor(p0[fm][reg], mask);
                p1[fm][reg] += __shfl_xor(p1[fm][reg], mask);
            }
    }
    if (lr == 0) {
#pragma unroll
        for (int fm = 0; fm < 2; fm++)
#pragma unroll
            for (int reg = 0; reg < 4; reg++) {
                int row = fm * 16 + g * 4 + reg;
                part[wave][row][0] = p0[fm][reg];
                part[wave][row][1] = p1[fm][reg];
            }
    }
    __syncthreads();
    if (t < 32) {
        int l = bm0 + t;
        if (l < NL) {
            float l0 = part[0][t][0] + part[1][t][0] + part[2][t][0] + part[3][t][0] + b2[0];
            float l1 = part[0][t][1] + part[1][t][1] + part[2][t][1] + part[3][t][1] + b2[1];
            float mx = fmaxf(l0, l1);
            float lse = mx + logf(expf(l0 - mx) + expf(l1 - mx));
            out[(size_t)l * 2 + 0] = l0 - lse;
            out[(size_t)l * 2 + 1] = l1 - lse;
        }
    }
}

extern "C" void kernel_launch(void* const* d_in, const int* in_sizes, int n_in,
                              void* d_out, int out_size, void* d_ws, size_t ws_size,
                              hipStream_t stream) {
    const float* x      = (const float*)d_in[0];
    const float* ex     = (const float*)d_in[1];
    const int*   ei     = (const int*)d_in[2];
    const int*   marks  = (const int*)d_in[3];
    const int*   emarks = (const int*)d_in[4];
    const float* Wn[3] = {(const float*)d_in[5],  (const float*)d_in[9],  (const float*)d_in[13]};
    const float* bn[3] = {(const float*)d_in[6],  (const float*)d_in[10], (const float*)d_in[14]};
    const float* We[3] = {(const float*)d_in[7],  (const float*)d_in[11], (const float*)d_in[15]};
    const float* be[3] = {(const float*)d_in[8],  (const float*)d_in[12], (const float*)d_in[16]};
    const float* W1 = (const float*)d_in[17];
    const float* b1 = (const float*)d_in[18];
    const float* W2 = (const float*)d_in[19];
    const float* b2 = (const float*)d_in[20];

    // ---- workspace layout ----
    int*    off_n = (int*)d_ws;                // 50004
    int*    off_h = off_n + 50004;             // 50004
    int*    adj_n = off_h + 50004;             // 800000
    int*    adj_h = adj_n + 800000;            // 800000
    int*    cnt   = adj_h + 800000;            // 100000
    int*    cur   = cnt + 100000;              // 100000
    int*    parts = cur + 100000;              // 512
    float*  invn  = (float*)(parts + 512);     // 50000
    float*  invh  = invn + 50000;              // 50000
    __half* xwb   = (__half*)(invh + 50000);   // 6.4M  (node table, sliced)
    __half* xwb2  = xwb + 6400000;             // 3.2M  (edge table, sliced)
    __half* heb   = xwb2 + 3200000;            // 6.4M
    __half* heb2  = heb + 6400000;             // 3.2M
    __half* h[3]  = {heb2 + 3200000, heb2 + 9600000, heb2 + 16000000};  // 6.4M each
    __half* g[3]  = {h[2] + 6400000, h[2] + 9600000, h[2] + 12800000};  // 3.2M each
    __half* Wnt[3] = {g[2] + 3200000, g[2] + 3232768, g[2] + 3249152};
    __half* Wet[3] = {g[2] + 3265536, g[2] + 3273728, g[2] + 3277824};
    __half* W1t    = g[2] + 3281920;

    int* cnt_n = cnt;
    int* cnt_h = cnt + 50000;
    int* cur_n = cur;
    int* cur_h = cur + 50000;

    // ---- prep + CSR build ----
    hipMemsetAsync(cnt, 0, 200000 * sizeof(int), stream);   // counts + cursors
    k_prep<<<WT_BLKS + HIST_SEGS * 8, 256, 0, stream>>>(
        Wn[0], Wn[1], Wn[2], We[0], We[1], We[2], W1,
        Wnt[0], Wnt[1], Wnt[2], Wet[0], Wet[1], Wet[2], W1t,
        ei, cnt_n, cnt_h);
    k_scanp1<<<392, 256, 0, stream>>>(cnt_n, cnt_h, parts);
    k_scanp2<<<2, 256, 0, stream>>>(parts, off_n, off_h);
    k_scanp3<<<392, 256, 0, stream>>>(cnt_n, cnt_h, parts, off_n, off_h, invn, invh);
    k_fill<<<FILL_SEGS * 8, 256, 0, stream>>>(ei, off_n, off_h, cur_n, cur_h, adj_n, adj_h);

    // ---- fused node+edge conv chains (sliced tables) ----
    k_gemm2<float><<<1564, 256, 0, stream>>>(x, Wnt[0], xwb, 256, ex, Wet[0], xwb2, 128);
    k_pull2<false><<<PULL_GRID, 256, 0, stream>>>(xwb, off_h, adj_h, invh, nullptr, heb,
                                                  xwb2, off_n, adj_n, invn, nullptr, heb2);
    k_pull2<true><<<PULL_GRID, 256, 0, stream>>>(heb, off_n, adj_n, invn, bn[0], h[0],
                                                 heb2, off_h, adj_h, invh, be[0], g[0]);
    for (int i = 1; i < 3; i++) {
        k_gemm2<__half><<<1564, 256, 0, stream>>>(h[i - 1], Wnt[i], xwb, 128,
                                                  g[i - 1], Wet[i], xwb2, 64);
        k_pull2<false><<<PULL_GRID, 256, 0, stream>>>(xwb, off_h, adj_h, invh, nullptr, heb,
                                                      xwb2, off_n, adj_n, invn, nullptr, heb2);
        k_pull2<true><<<PULL_GRID, 256, 0, stream>>>(heb, off_n, adj_n, invn, bn[i], h[i],
                                                     heb2, off_h, adj_h, invh, be[i], g[i]);
    }

    // ---- fused final MLP (MFMA) + head + log_softmax ----
    k_mlp_mfma<<<(NL + 31) / 32, 256, 0, stream>>>(h[0], h[1], h[2], g[0], g[1], g[2],
                                                   marks, emarks, W1t, b1, W2, b2, (float*)d_out);
}

// Round 15
// 609.408 us; speedup vs baseline: 1.1173x; 1.1173x over previous
//
#include <hip/hip_runtime.h>
#include <hip/hip_fp16.h>
#include <math.h>

#define NN 50000
#define NH 50000
#define NI 800000
#define NL 20000

using half8 = __attribute__((ext_vector_type(8))) _Float16;
using f32x4 = __attribute__((ext_vector_type(4))) float;

// ================= helpers =================
static __device__ __forceinline__ float2 pack_h4(float4 v) {
    float2 st;
    *(__half2*)&st.x = __float22half2_rn(make_float2(v.x, v.y));
    *(__half2*)&st.y = __float22half2_rn(make_float2(v.z, v.w));
    return st;
}
static __device__ __forceinline__ void acc_h8(float4& a, float4& b, float4 raw) {
    const __half2* hp = (const __half2*)&raw;
    float2 f0 = __half22float2(hp[0]);
    float2 f1 = __half22float2(hp[1]);
    float2 f2 = __half22float2(hp[2]);
    float2 f3 = __half22float2(hp[3]);
    a.x += f0.x; a.y += f0.y; a.z += f1.x; a.w += f1.y;
    b.x += f2.x; b.y += f2.y; b.z += f3.x; b.w += f3.y;
}
static __device__ __forceinline__ float4 pack_h8(float4 a, float4 b) {
    float4 st;
    ((__half2*)&st)[0] = __float22half2_rn(make_float2(a.x, a.y));
    ((__half2*)&st)[1] = __float22half2_rn(make_float2(a.z, a.w));
    ((__half2*)&st)[2] = __float22half2_rn(make_float2(b.x, b.y));
    ((__half2*)&st)[3] = __float22half2_rn(make_float2(b.z, b.w));
    return st;
}
static __device__ __forceinline__ void nt_store_half(__half v, __half* p) {
    unsigned short u = *(unsigned short*)&v;
    __builtin_nontemporal_store(u, (unsigned short*)p);
}
static __device__ __forceinline__ void nt_store_f4(float4 v, void* p) {
    f32x4 u = *(f32x4*)&v;
    __builtin_nontemporal_store(u, (f32x4*)p);
}

// ================= prep: 7 weight transposes + XCD-bucketed histogram ==========
#define WT_BLKS 1088
#define HIST_SEGS 98
#define HIST_PER  8164
__global__ void k_prep(const float* __restrict__ Wn0, const float* __restrict__ Wn1,
                       const float* __restrict__ Wn2, const float* __restrict__ We0,
                       const float* __restrict__ We1, const float* __restrict__ We2,
                       const float* __restrict__ W1,
                       __half* __restrict__ Wnt0, __half* __restrict__ Wnt1,
                       __half* __restrict__ Wnt2, __half* __restrict__ Wet0,
                       __half* __restrict__ Wet1, __half* __restrict__ Wet2,
                       __half* __restrict__ W1t,
                       const int* __restrict__ ei, int* __restrict__ cnt_n,
                       int* __restrict__ cnt_h) {
    int b = blockIdx.x, t = threadIdx.x;
    if (b < WT_BLKS) {
        int u = b * 256 + t;
        if (u < 278528) {
            const float* S; __half* D; int K, N;
            if (u < 32768)      { S = Wn0; D = Wnt0; K = 256; N = 128; }
            else if (u < 49152) { S = Wn1; D = Wnt1; K = 128; N = 128; u -= 32768; }
            else if (u < 65536) { S = Wn2; D = Wnt2; K = 128; N = 128; u -= 49152; }
            else if (u < 73728) { S = We0; D = Wet0; K = 128; N = 64;  u -= 65536; }
            else if (u < 77824) { S = We1; D = Wet1; K = 64;  N = 64;  u -= 73728; }
            else if (u < 81920) { S = We2; D = Wet2; K = 64;  N = 64;  u -= 77824; }
            else                { S = W1;  D = W1t;  K = 768; N = 256; u -= 81920; }
            int n = u / K, k = u % K;
            D[(size_t)n * K + k] = __float2half(S[(size_t)k * N + n]);
        }
    } else {
        int hb = b - WT_BLKS;
        int bucket = hb & 7;
        int seg = hb >> 3;
        int lo = seg * HIST_PER;
        int hi = min(lo + HIST_PER, NI);
        for (int e = lo + t; e < hi; e += 256) {
            int s = __builtin_nontemporal_load(&ei[e]);
            int d = __builtin_nontemporal_load(&ei[e + NI]);
            if (s / 6250 == bucket) atomicAdd(&cnt_n[s], 1);
            if (d / 6250 == bucket) atomicAdd(&cnt_h[d], 1);
        }
    }
}

// ================= 3-phase multi-block scan =================
__global__ void k_scanp1(const int* __restrict__ cnt_n, const int* __restrict__ cnt_h,
                         int* __restrict__ parts) {
    __shared__ int s[256];
    int arr = blockIdx.x / 196, blk = blockIdx.x % 196, t = threadIdx.x;
    const int* cnt = arr ? cnt_h : cnt_n;
    int i = blk * 256 + t;
    int v = (i < 50000) ? cnt[i] : 0;
    s[t] = v;
    __syncthreads();
#pragma unroll
    for (int d = 128; d > 0; d >>= 1) {
        if (t < d) s[t] += s[t + d];
        __syncthreads();
    }
    if (t == 0) parts[arr * 256 + blk] = s[0];
}

__global__ void k_scanp2(int* __restrict__ parts, int* __restrict__ off_n,
                         int* __restrict__ off_h) {
    __shared__ int s[256];
    int b = blockIdx.x, t = threadIdx.x;
    int* P = parts + b * 256;
    int v = (t < 196) ? P[t] : 0;
    s[t] = v;
    __syncthreads();
#pragma unroll
    for (int d = 1; d < 256; d <<= 1) {
        int u = (t >= d) ? s[t - d] : 0;
        __syncthreads();
        s[t] += u;
        __syncthreads();
    }
    if (t < 196) P[t] = s[t] - v;          // exclusive
    if (t == 0) {
        int* off = b ? off_h : off_n;
        off[50000] = s[255];
    }
}

__global__ void k_scanp3(const int* __restrict__ cnt_n, const int* __restrict__ cnt_h,
                         const int* __restrict__ parts, int* __restrict__ off_n,
                         int* __restrict__ off_h, float* __restrict__ invn,
                         float* __restrict__ invh) {
    __shared__ int s[256];
    int arr = blockIdx.x / 196, blk = blockIdx.x % 196, t = threadIdx.x;
    const int* cnt = arr ? cnt_h : cnt_n;
    int* off = arr ? off_h : off_n;
    float* inv = arr ? invh : invn;
    int i = blk * 256 + t;
    int c = (i < 50000) ? cnt[i] : 0;
    s[t] = c;
    __syncthreads();
#pragma unroll
    for (int d = 1; d < 256; d <<= 1) {
        int u = (t >= d) ? s[t - d] : 0;
        __syncthreads();
        s[t] += u;
        __syncthreads();
    }
    if (i < 50000) {
        off[i] = parts[arr * 256 + blk] + s[t] - c;
        inv[i] = c > 0 ? 1.0f / (float)c : 0.0f;
    }
}

// ================= XCD-bucketed CSR fill (nontemporal ei stream) =================
#define FILL_SEGS 98
#define FILL_PER  8164
__global__ void k_fill(const int* __restrict__ ei, const int* __restrict__ off_n,
                       const int* __restrict__ off_h, int* __restrict__ cur_n,
                       int* __restrict__ cur_h, int* __restrict__ adj_n,
                       int* __restrict__ adj_h) {
    int bucket = blockIdx.x & 7;
    int seg = blockIdx.x >> 3;
    int lo = seg * FILL_PER;
    int hi = min(lo + FILL_PER, NI);
    for (int e = lo + (int)threadIdx.x; e < hi; e += 256) {
        int s = __builtin_nontemporal_load(&ei[e]);
        int d = __builtin_nontemporal_load(&ei[e + NI]);
        if (d / 6250 == bucket) {
            int p = atomicAdd(&cur_h[d], 1);
            adj_h[off_h[d] + p] = s;
        }
        if (s / 6250 == bucket) {
            int q = atomicAdd(&cur_n[s], 1);
            adj_n[off_n[s] + q] = d;
        }
    }
}

// ================= MFMA GEMM body (row-major tables) =================
template <typename SrcT, int BM, int BN, int FM, int FN>
static __device__ __forceinline__ void gemm_body(const SrcT* __restrict__ X,
                                                 const __half* __restrict__ Wt,
                                                 __half* __restrict__ Y, int M, int K,
                                                 int blk, __half* smem) {
    constexpr int LDK = 56;
    constexpr int WN = BN / 4;
    __half* Xs = smem;
    __half* Ws = smem + BM * LDK;
    int t = threadIdx.x;
    int wave = t >> 6, lane = t & 63;
    int g = lane >> 4, lr = lane & 15;
    int bm0 = blk * BM;
    f32x4 acc[FM][FN] = {};

    for (int k0 = 0; k0 < K; k0 += 32) {
        for (int u = t; u < BM * 4; u += 256) {
            int r = u >> 2, q = u & 3;
            int rg = bm0 + r; if (rg >= M) rg = M - 1;
            if constexpr (sizeof(SrcT) == 4) {
                const float* src = (const float*)X + (size_t)rg * K + k0 + q * 8;
                float4 v0 = *(const float4*)src;
                float4 v1 = *(const float4*)(src + 4);
                *(float2*)&Xs[r * LDK + q * 8]     = pack_h4(v0);
                *(float2*)&Xs[r * LDK + q * 8 + 4] = pack_h4(v1);
            } else {
                *(float4*)&Xs[r * LDK + q * 8] =
                    *(const float4*)((const __half*)X + (size_t)rg * K + k0 + q * 8);
            }
        }
        for (int u = t; u < BN * 4; u += 256) {
            int r = u >> 2, q = u & 3;
            *(float4*)&Ws[r * LDK + q * 8] = *(const float4*)&Wt[(size_t)r * K + k0 + q * 8];
        }
        __syncthreads();
        half8 a[FM], b[FN];
#pragma unroll
        for (int fm = 0; fm < FM; fm++)
            a[fm] = *(const half8*)&Xs[(fm * 16 + lr) * LDK + g * 8];
#pragma unroll
        for (int fn = 0; fn < FN; fn++)
            b[fn] = *(const half8*)&Ws[(wave * WN + fn * 16 + lr) * LDK + g * 8];
#pragma unroll
        for (int fm = 0; fm < FM; fm++)
#pragma unroll
            for (int fn = 0; fn < FN; fn++)
                acc[fm][fn] = __builtin_amdgcn_mfma_f32_16x16x32_f16(a[fm], b[fn], acc[fm][fn], 0, 0, 0);
        __syncthreads();
    }
#pragma unroll
    for (int fm = 0; fm < FM; fm++) {
#pragma unroll
        for (int fn = 0; fn < FN; fn++) {
            int cg = wave * WN + fn * 16 + lr;
#pragma unroll
            for (int reg = 0; reg < 4; reg++) {
                int rg = bm0 + fm * 16 + g * 4 + reg;
                if (rg < M)
                    nt_store_half(__float2half(acc[fm][fn][reg]), &Y[(size_t)rg * BN + cg]);
            }
        }
    }
}

template <typename SrcT>
__global__ void __launch_bounds__(256)
k_gemm2(const SrcT* __restrict__ Xn, const __half* __restrict__ Wtn,
        __half* __restrict__ Yn, int Kn,
        const SrcT* __restrict__ Xe, const __half* __restrict__ Wte,
        __half* __restrict__ Ye, int Ke) {
    __shared__ __align__(16) __half smem[(64 + 128) * 56];
    if (blockIdx.x < 782)
        gemm_body<SrcT, 64, 128, 4, 2>(Xn, Wtn, Yn, NN, Kn, blockIdx.x, smem);
    else
        gemm_body<SrcT, 64, 64, 4, 1>(Xe, Wte, Ye, NH, Ke, blockIdx.x - 782, smem);
}

// ================= pull body: 16B gathers, 8-way unrolled, nt adj/out ========
template <int F, bool RELU>
static __device__ __forceinline__ void pull_body(const __half* __restrict__ in,
                                                 const int* __restrict__ off,
                                                 const int* __restrict__ adj,
                                                 const float* __restrict__ scale,
                                                 const float* __restrict__ bias,
                                                 __half* __restrict__ out,
                                                 int nrows, int blk) {
    constexpr int TPR = F / 8;
    constexpr int RPB = 256 / TPR;
    int r = blk * RPB + (int)threadIdx.x / TPR;
    int lane = threadIdx.x % TPR;
    if (r >= nrows) return;
    int lo = off[r], hi = off[r + 1];
    const float4* in4 = (const float4*)in;
    float4 a0 = {0,0,0,0}, b0 = {0,0,0,0}, a1 = {0,0,0,0}, b1v = {0,0,0,0};
    float4 a2 = {0,0,0,0}, b2v = {0,0,0,0}, a3 = {0,0,0,0}, b3 = {0,0,0,0};
    int j = lo;
    for (; j + 7 < hi; j += 8) {
        int c0 = __builtin_nontemporal_load(&adj[j]);
        int c1 = __builtin_nontemporal_load(&adj[j + 1]);
        int c2 = __builtin_nontemporal_load(&adj[j + 2]);
        int c3 = __builtin_nontemporal_load(&adj[j + 3]);
        int c4 = __builtin_nontemporal_load(&adj[j + 4]);
        int c5 = __builtin_nontemporal_load(&adj[j + 5]);
        int c6 = __builtin_nontemporal_load(&adj[j + 6]);
        int c7 = __builtin_nontemporal_load(&adj[j + 7]);
        float4 v0 = in4[(size_t)c0 * TPR + lane];
        float4 v1 = in4[(size_t)c1 * TPR + lane];
        float4 v2 = in4[(size_t)c2 * TPR + lane];
        float4 v3 = in4[(size_t)c3 * TPR + lane];
        float4 v4 = in4[(size_t)c4 * TPR + lane];
        float4 v5 = in4[(size_t)c5 * TPR + lane];
        float4 v6 = in4[(size_t)c6 * TPR + lane];
        float4 v7 = in4[(size_t)c7 * TPR + lane];
        acc_h8(a0, b0, v0); acc_h8(a1, b1v, v1); acc_h8(a2, b2v, v2); acc_h8(a3, b3, v3);
        acc_h8(a0, b0, v4); acc_h8(a1, b1v, v5); acc_h8(a2, b2v, v6); acc_h8(a3, b3, v7);
    }
    for (; j + 1 < hi; j += 2) {
        int c0 = adj[j], c1 = adj[j + 1];
        float4 v0 = in4[(size_t)c0 * TPR + lane];
        float4 v1 = in4[(size_t)c1 * TPR + lane];
        acc_h8(a0, b0, v0); acc_h8(a1, b1v, v1);
    }
    if (j < hi) {
        float4 v0 = in4[(size_t)adj[j] * TPR + lane];
        acc_h8(a0, b0, v0);
    }
    a0.x += a1.x + a2.x + a3.x; a0.y += a1.y + a2.y + a3.y;
    a0.z += a1.z + a2.z + a3.z; a0.w += a1.w + a2.w + a3.w;
    b0.x += b1v.x + b2v.x + b3.x; b0.y += b1v.y + b2v.y + b3.y;
    b0.z += b1v.z + b2v.z + b3.z; b0.w += b1v.w + b2v.w + b3.w;
    float sc = scale[r];
    if (RELU) {
        float4 ba = ((const float4*)bias)[lane * 2];
        float4 bb = ((const float4*)bias)[lane * 2 + 1];
        a0.x = fmaxf(fmaf(a0.x, sc, ba.x), 0.f);
        a0.y = fmaxf(fmaf(a0.y, sc, ba.y), 0.f);
        a0.z = fmaxf(fmaf(a0.z, sc, ba.z), 0.f);
        a0.w = fmaxf(fmaf(a0.w, sc, ba.w), 0.f);
        b0.x = fmaxf(fmaf(b0.x, sc, bb.x), 0.f);
        b0.y = fmaxf(fmaf(b0.y, sc, bb.y), 0.f);
        b0.z = fmaxf(fmaf(b0.z, sc, bb.z), 0.f);
        b0.w = fmaxf(fmaf(b0.w, sc, bb.w), 0.f);
    } else {
        a0.x *= sc; a0.y *= sc; a0.z *= sc; a0.w *= sc;
        b0.x *= sc; b0.y *= sc; b0.z *= sc; b0.w *= sc;
    }
    nt_store_f4(pack_h8(a0, b0), &((float4*)out)[(size_t)r * TPR + lane]);
}

// combined pull: blocks [0,3125) = F=128 side, [3125,4688) = F=64 side
template <bool RELU>
__global__ void k_pull2(const __half* __restrict__ inA, const int* __restrict__ offA,
                        const int* __restrict__ adjA, const float* __restrict__ scA,
                        const float* __restrict__ biA, __half* __restrict__ outA, int rowsA,
                        const __half* __restrict__ inB, const int* __restrict__ offB,
                        const int* __restrict__ adjB, const float* __restrict__ scB,
                        const float* __restrict__ biB, __half* __restrict__ outB, int rowsB) {
    if (blockIdx.x < 3125)
        pull_body<128, RELU>(inA, offA, adjA, scA, biA, outA, rowsA, blockIdx.x);
    else
        pull_body<64, RELU>(inB, offB, adjB, scB, biB, outB, rowsB, blockIdx.x - 3125);
}

// ================= fused final MLP via MFMA ==================================
__global__ void __launch_bounds__(256)
k_mlp_mfma(const __half* __restrict__ hx1, const __half* __restrict__ hx2,
           const __half* __restrict__ hx3, const __half* __restrict__ gx1,
           const __half* __restrict__ gx2, const __half* __restrict__ gx3,
           const int* __restrict__ marks, const int* __restrict__ emarks,
           const __half* __restrict__ W1t, const float* __restrict__ b1,
           const float* __restrict__ W2, const float* __restrict__ b2,
           float* __restrict__ out) {
    constexpr int LDK = 56;
    __shared__ __align__(16) __half Xs[32 * LDK];
    __shared__ __align__(16) __half Ws[256 * LDK];
    __shared__ float part[4][32][2];
    int t = threadIdx.x;
    int wave = t >> 6, lane = t & 63;
    int g = lane >> 4, lr = lane & 15;
    int bm0 = blockIdx.x * 32;
    int r_s = t >> 2, q_s = t & 3;
    int m_s = 0, e_s = 0;
    if (t < 128) {
        int l = bm0 + r_s; if (l >= NL) l = NL - 1;
        m_s = marks[l]; e_s = emarks[l];
    }
    f32x4 acc[2][4] = {};

    for (int k0 = 0; k0 < 768; k0 += 32) {
        if (t < 128) {
            if (k0 < 384) {
                int fb = (k0 < 192 ? k0 : k0 - 192) + q_s * 8;
                const __half* gs = fb < 64 ? gx1 : (fb < 128 ? gx2 : gx3);
                int off = fb & 63;
                half8 va = *(const half8*)&gs[(size_t)e_s * 64 + off];
                half8 vb = *(const half8*)&gs[(size_t)(e_s + 1) * 64 + off];
                half8 rv;
                if (k0 < 192) {
#pragma unroll
                    for (int j = 0; j < 8; j++)
                        rv[j] = (_Float16)fminf((float)va[j], (float)vb[j]);
                } else {
#pragma unroll
                    for (int j = 0; j < 8; j++)
                        rv[j] = (_Float16)fmaxf((float)va[j], (float)vb[j]);
                }
                *(half8*)&Xs[r_s * LDK + q_s * 8] = rv;
            } else {
                int fb = (k0 - 384) + q_s * 8;
                const __half* hs = fb < 128 ? hx1 : (fb < 256 ? hx2 : hx3);
                int off = fb & 127;
                *(float4*)&Xs[r_s * LDK + q_s * 8] = *(const float4*)&hs[(size_t)m_s * 128 + off];
            }
        }
        for (int u = t; u < 1024; u += 256) {
            int r = u >> 2, q = u & 3;
            *(float4*)&Ws[r * LDK + q * 8] = *(const float4*)&W1t[(size_t)r * 768 + k0 + q * 8];
        }
        __syncthreads();
        half8 a[2], b[4];
#pragma unroll
        for (int fm = 0; fm < 2; fm++)
            a[fm] = *(const half8*)&Xs[(fm * 16 + lr) * LDK + g * 8];
#pragma unroll
        for (int fn = 0; fn < 4; fn++)
            b[fn] = *(const half8*)&Ws[(wave * 64 + fn * 16 + lr) * LDK + g * 8];
#pragma unroll
        for (int fm = 0; fm < 2; fm++)
#pragma unroll
            for (int fn = 0; fn < 4; fn++)
                acc[fm][fn] = __builtin_amdgcn_mfma_f32_16x16x32_f16(a[fm], b[fn], acc[fm][fn], 0, 0, 0);
        __syncthreads();
    }
    float b1c[4], w20[4], w21[4];
#pragma unroll
    for (int fn = 0; fn < 4; fn++) {
        int col = wave * 64 + fn * 16 + lr;
        b1c[fn] = b1[col];
        w20[fn] = W2[(size_t)col * 2 + 0];
        w21[fn] = W2[(size_t)col * 2 + 1];
    }
    float p0[2][4], p1[2][4];
#pragma unroll
    for (int fm = 0; fm < 2; fm++) {
#pragma unroll
        for (int reg = 0; reg < 4; reg++) {
            float s0 = 0.f, s1 = 0.f;
#pragma unroll
            for (int fn = 0; fn < 4; fn++) {
                float hh = fmaxf(acc[fm][fn][reg] + b1c[fn], 0.f);
                s0 = fmaf(hh, w20[fn], s0);
                s1 = fmaf(hh, w21[fn], s1);
            }
            p0[fm][reg] = s0; p1[fm][reg] = s1;
        }
    }
#pragma unroll
    for (int mask = 1; mask < 16; mask <<= 1) {
#pragma unroll
        for (int fm = 0; fm < 2; fm++)
#pragma unroll
            for (int reg = 0; reg < 4; reg++) {
                p0[fm][reg] += __shfl_xor(p0[fm][reg], mask);
                p1[fm][reg] += __shfl_xor(p1[fm][reg], mask);
            }
    }
    if (lr == 0) {
#pragma unroll
        for (int fm = 0; fm < 2; fm++)
#pragma unroll
            for (int reg = 0; reg < 4; reg++) {
                int row = fm * 16 + g * 4 + reg;
                part[wave][row][0] = p0[fm][reg];
                part[wave][row][1] = p1[fm][reg];
            }
    }
    __syncthreads();
    if (t < 32) {
        int l = bm0 + t;
        if (l < NL) {
            float l0 = part[0][t][0] + part[1][t][0] + part[2][t][0] + part[3][t][0] + b2[0];
            float l1 = part[0][t][1] + part[1][t][1] + part[2][t][1] + part[3][t][1] + b2[1];
            float mx = fmaxf(l0, l1);
            float lse = mx + logf(expf(l0 - mx) + expf(l1 - mx));
            out[(size_t)l * 2 + 0] = l0 - lse;
            out[(size_t)l * 2 + 1] = l1 - lse;
        }
    }
}

extern "C" void kernel_launch(void* const* d_in, const int* in_sizes, int n_in,
                              void* d_out, int out_size, void* d_ws, size_t ws_size,
                              hipStream_t stream) {
    const float* x      = (const float*)d_in[0];
    const float* ex     = (const float*)d_in[1];
    const int*   ei     = (const int*)d_in[2];
    const int*   marks  = (const int*)d_in[3];
    const int*   emarks = (const int*)d_in[4];
    const float* Wn[3] = {(const float*)d_in[5],  (const float*)d_in[9],  (const float*)d_in[13]};
    const float* bn[3] = {(const float*)d_in[6],  (const float*)d_in[10], (const float*)d_in[14]};
    const float* We[3] = {(const float*)d_in[7],  (const float*)d_in[11], (const float*)d_in[15]};
    const float* be[3] = {(const float*)d_in[8],  (const float*)d_in[12], (const float*)d_in[16]};
    const float* W1 = (const float*)d_in[17];
    const float* b1 = (const float*)d_in[18];
    const float* W2 = (const float*)d_in[19];
    const float* b2 = (const float*)d_in[20];

    // ---- workspace layout ----
    int*    off_n = (int*)d_ws;                // 50004
    int*    off_h = off_n + 50004;             // 50004
    int*    adj_n = off_h + 50004;             // 800000
    int*    adj_h = adj_n + 800000;            // 800000
    int*    cnt   = adj_h + 800000;            // 100000
    int*    cur   = cnt + 100000;              // 100000
    int*    parts = cur + 100000;              // 512
    float*  invn  = (float*)(parts + 512);     // 50000
    float*  invh  = invn + 50000;              // 50000
    __half* xwb   = (__half*)(invh + 50000);   // 6.4M
    __half* xwb2  = xwb + 6400000;             // 3.2M
    __half* heb   = xwb2 + 3200000;            // 6.4M
    __half* heb2  = heb + 6400000;             // 3.2M
    __half* h[3]  = {heb2 + 3200000, heb2 + 9600000, heb2 + 16000000};  // 6.4M each
    __half* g[3]  = {h[2] + 6400000, h[2] + 9600000, h[2] + 12800000};  // 3.2M each
    __half* Wnt[3] = {g[2] + 3200000, g[2] + 3232768, g[2] + 3249152};
    __half* Wet[3] = {g[2] + 3265536, g[2] + 3273728, g[2] + 3277824};
    __half* W1t    = g[2] + 3281920;

    int* cnt_n = cnt;
    int* cnt_h = cnt + 50000;
    int* cur_n = cur;
    int* cur_h = cur + 50000;

    // ---- prep + CSR build ----
    hipMemsetAsync(cnt, 0, 200000 * sizeof(int), stream);   // counts + cursors
    k_prep<<<WT_BLKS + HIST_SEGS * 8, 256, 0, stream>>>(
        Wn[0], Wn[1], Wn[2], We[0], We[1], We[2], W1,
        Wnt[0], Wnt[1], Wnt[2], Wet[0], Wet[1], Wet[2], W1t,
        ei, cnt_n, cnt_h);
    k_scanp1<<<392, 256, 0, stream>>>(cnt_n, cnt_h, parts);
    k_scanp2<<<2, 256, 0, stream>>>(parts, off_n, off_h);
    k_scanp3<<<392, 256, 0, stream>>>(cnt_n, cnt_h, parts, off_n, off_h, invn, invh);
    k_fill<<<FILL_SEGS * 8, 256, 0, stream>>>(ei, off_n, off_h, cur_n, cur_h, adj_n, adj_h);

    // ---- fused node+edge conv chains ----
    k_gemm2<float><<<1564, 256, 0, stream>>>(x, Wnt[0], xwb, 256, ex, Wet[0], xwb2, 128);
    k_pull2<false><<<4688, 256, 0, stream>>>(xwb, off_h, adj_h, invh, nullptr, heb, NH,
                                             xwb2, off_n, adj_n, invn, nullptr, heb2, NN);
    k_pull2<true><<<4688, 256, 0, stream>>>(heb, off_n, adj_n, invn, bn[0], h[0], NN,
                                            heb2, off_h, adj_h, invh, be[0], g[0], NH);
    for (int i = 1; i < 3; i++) {
        k_gemm2<__half><<<1564, 256, 0, stream>>>(h[i - 1], Wnt[i], xwb, 128,
                                                  g[i - 1], Wet[i], xwb2, 64);
        k_pull2<false><<<4688, 256, 0, stream>>>(xwb, off_h, adj_h, invh, nullptr, heb, NH,
                                                 xwb2, off_n, adj_n, invn, nullptr, heb2, NN);
        k_pull2<true><<<4688, 256, 0, stream>>>(heb, off_n, adj_n, invn, bn[i], h[i], NN,
                                                heb2, off_h, adj_h, invh, be[i], g[i], NH);
    }

    // ---- fused final MLP (MFMA) + head + log_softmax ----
    k_mlp_mfma<<<(NL + 31) / 32, 256, 0, stream>>>(h[0], h[1], h[2], g[0], g[1], g[2],
                                                   marks, emarks, W1t, b1, W2, b2, (float*)d_out);
}

// Round 16
// 558.078 us; speedup vs baseline: 1.2201x; 1.0920x over previous
//
#include <hip/hip_runtime.h>
#include <hip/hip_fp16.h>
#include <math.h>

#define NN 50000
#define NH 50000
#define NI 800000
#define NL 20000

using half8 = __attribute__((ext_vector_type(8))) _Float16;
using f32x4 = __attribute__((ext_vector_type(4))) float;

// ================= helpers =================
static __device__ __forceinline__ float2 pack_h4(float4 v) {
    float2 st;
    *(__half2*)&st.x = __float22half2_rn(make_float2(v.x, v.y));
    *(__half2*)&st.y = __float22half2_rn(make_float2(v.z, v.w));
    return st;
}
static __device__ __forceinline__ void acc_h8(float4& a, float4& b, float4 raw) {
    const __half2* hp = (const __half2*)&raw;
    float2 f0 = __half22float2(hp[0]);
    float2 f1 = __half22float2(hp[1]);
    float2 f2 = __half22float2(hp[2]);
    float2 f3 = __half22float2(hp[3]);
    a.x += f0.x; a.y += f0.y; a.z += f1.x; a.w += f1.y;
    b.x += f2.x; b.y += f2.y; b.z += f3.x; b.w += f3.y;
}
static __device__ __forceinline__ float4 pack_h8(float4 a, float4 b) {
    float4 st;
    ((__half2*)&st)[0] = __float22half2_rn(make_float2(a.x, a.y));
    ((__half2*)&st)[1] = __float22half2_rn(make_float2(a.z, a.w));
    ((__half2*)&st)[2] = __float22half2_rn(make_float2(b.x, b.y));
    ((__half2*)&st)[3] = __float22half2_rn(make_float2(b.z, b.w));
    return st;
}

// ================= prep: 7 weight transposes + XCD-bucketed histogram ==========
#define WT_BLKS 1088
#define HIST_SEGS 98
#define HIST_PER  8164
__global__ void k_prep(const float* __restrict__ Wn0, const float* __restrict__ Wn1,
                       const float* __restrict__ Wn2, const float* __restrict__ We0,
                       const float* __restrict__ We1, const float* __restrict__ We2,
                       const float* __restrict__ W1,
                       __half* __restrict__ Wnt0, __half* __restrict__ Wnt1,
                       __half* __restrict__ Wnt2, __half* __restrict__ Wet0,
                       __half* __restrict__ Wet1, __half* __restrict__ Wet2,
                       __half* __restrict__ W1t,
                       const int* __restrict__ ei, int* __restrict__ cnt_n,
                       int* __restrict__ cnt_h) {
    int b = blockIdx.x, t = threadIdx.x;
    if (b < WT_BLKS) {
        int u = b * 256 + t;
        if (u < 278528) {
            const float* S; __half* D; int K, N;
            if (u < 32768)      { S = Wn0; D = Wnt0; K = 256; N = 128; }
            else if (u < 49152) { S = Wn1; D = Wnt1; K = 128; N = 128; u -= 32768; }
            else if (u < 65536) { S = Wn2; D = Wnt2; K = 128; N = 128; u -= 49152; }
            else if (u < 73728) { S = We0; D = Wet0; K = 128; N = 64;  u -= 65536; }
            else if (u < 77824) { S = We1; D = Wet1; K = 64;  N = 64;  u -= 73728; }
            else if (u < 81920) { S = We2; D = Wet2; K = 64;  N = 64;  u -= 77824; }
            else                { S = W1;  D = W1t;  K = 768; N = 256; u -= 81920; }
            int n = u / K, k = u % K;
            D[(size_t)n * K + k] = __float2half(S[(size_t)k * N + n]);
        }
    } else {
        int hb = b - WT_BLKS;
        int bucket = hb & 7;
        int seg = hb >> 3;
        int lo = seg * HIST_PER;
        int hi = min(lo + HIST_PER, NI);
        for (int e = lo + t; e < hi; e += 256) {
            int s = ei[e], d = ei[e + NI];
            if (s / 6250 == bucket) atomicAdd(&cnt_n[s], 1);
            if (d / 6250 == bucket) atomicAdd(&cnt_h[d], 1);
        }
    }
}

// ================= 3-phase multi-block scan =================
__global__ void k_scanp1(const int* __restrict__ cnt_n, const int* __restrict__ cnt_h,
                         int* __restrict__ parts) {
    __shared__ int s[256];
    int arr = blockIdx.x / 196, blk = blockIdx.x % 196, t = threadIdx.x;
    const int* cnt = arr ? cnt_h : cnt_n;
    int i = blk * 256 + t;
    int v = (i < 50000) ? cnt[i] : 0;
    s[t] = v;
    __syncthreads();
#pragma unroll
    for (int d = 128; d > 0; d >>= 1) {
        if (t < d) s[t] += s[t + d];
        __syncthreads();
    }
    if (t == 0) parts[arr * 256 + blk] = s[0];
}

__global__ void k_scanp2(int* __restrict__ parts, int* __restrict__ off_n,
                         int* __restrict__ off_h) {
    __shared__ int s[256];
    int b = blockIdx.x, t = threadIdx.x;
    int* P = parts + b * 256;
    int v = (t < 196) ? P[t] : 0;
    s[t] = v;
    __syncthreads();
#pragma unroll
    for (int d = 1; d < 256; d <<= 1) {
        int u = (t >= d) ? s[t - d] : 0;
        __syncthreads();
        s[t] += u;
        __syncthreads();
    }
    if (t < 196) P[t] = s[t] - v;          // exclusive
    if (t == 0) {
        int* off = b ? off_h : off_n;
        off[50000] = s[255];
    }
}

__global__ void k_scanp3(const int* __restrict__ cnt_n, const int* __restrict__ cnt_h,
                         const int* __restrict__ parts, int* __restrict__ off_n,
                         int* __restrict__ off_h, float* __restrict__ invn,
                         float* __restrict__ invh) {
    __shared__ int s[256];
    int arr = blockIdx.x / 196, blk = blockIdx.x % 196, t = threadIdx.x;
    const int* cnt = arr ? cnt_h : cnt_n;
    int* off = arr ? off_h : off_n;
    float* inv = arr ? invh : invn;
    int i = blk * 256 + t;
    int c = (i < 50000) ? cnt[i] : 0;
    s[t] = c;
    __syncthreads();
#pragma unroll
    for (int d = 1; d < 256; d <<= 1) {
        int u = (t >= d) ? s[t - d] : 0;
        __syncthreads();
        s[t] += u;
        __syncthreads();
    }
    if (i < 50000) {
        off[i] = parts[arr * 256 + blk] + s[t] - c;
        inv[i] = c > 0 ? 1.0f / (float)c : 0.0f;
    }
}

// ================= MFMA GEMM body (row-major tables) =================
template <typename SrcT, int BM, int BN, int FM, int FN>
static __device__ __forceinline__ void gemm_body(const SrcT* __restrict__ X,
                                                 const __half* __restrict__ Wt,
                                                 __half* __restrict__ Y, int M, int K,
                                                 int blk, __half* smem) {
    constexpr int LDK = 56;
    constexpr int WN = BN / 4;
    __half* Xs = smem;
    __half* Ws = smem + BM * LDK;
    int t = threadIdx.x;
    int wave = t >> 6, lane = t & 63;
    int g = lane >> 4, lr = lane & 15;
    int bm0 = blk * BM;
    f32x4 acc[FM][FN] = {};

    for (int k0 = 0; k0 < K; k0 += 32) {
        for (int u = t; u < BM * 4; u += 256) {
            int r = u >> 2, q = u & 3;
            int rg = bm0 + r; if (rg >= M) rg = M - 1;
            if constexpr (sizeof(SrcT) == 4) {
                const float* src = (const float*)X + (size_t)rg * K + k0 + q * 8;
                float4 v0 = *(const float4*)src;
                float4 v1 = *(const float4*)(src + 4);
                *(float2*)&Xs[r * LDK + q * 8]     = pack_h4(v0);
                *(float2*)&Xs[r * LDK + q * 8 + 4] = pack_h4(v1);
            } else {
                *(float4*)&Xs[r * LDK + q * 8] =
                    *(const float4*)((const __half*)X + (size_t)rg * K + k0 + q * 8);
            }
        }
        for (int u = t; u < BN * 4; u += 256) {
            int r = u >> 2, q = u & 3;
            *(float4*)&Ws[r * LDK + q * 8] = *(const float4*)&Wt[(size_t)r * K + k0 + q * 8];
        }
        __syncthreads();
        half8 a[FM], b[FN];
#pragma unroll
        for (int fm = 0; fm < FM; fm++)
            a[fm] = *(const half8*)&Xs[(fm * 16 + lr) * LDK + g * 8];
#pragma unroll
        for (int fn = 0; fn < FN; fn++)
            b[fn] = *(const half8*)&Ws[(wave * WN + fn * 16 + lr) * LDK + g * 8];
#pragma unroll
        for (int fm = 0; fm < FM; fm++)
#pragma unroll
            for (int fn = 0; fn < FN; fn++)
                acc[fm][fn] = __builtin_amdgcn_mfma_f32_16x16x32_f16(a[fm], b[fn], acc[fm][fn], 0, 0, 0);
        __syncthreads();
    }
#pragma unroll
    for (int fm = 0; fm < FM; fm++) {
#pragma unroll
        for (int fn = 0; fn < FN; fn++) {
            int cg = wave * WN + fn * 16 + lr;
#pragma unroll
            for (int reg = 0; reg < 4; reg++) {
                int rg = bm0 + fm * 16 + g * 4 + reg;
                if (rg < M) Y[(size_t)rg * BN + cg] = __float2half(acc[fm][fn][reg]);
            }
        }
    }
}

// ================= merged: XCD-bucketed CSR fill + layer-0 GEMMs ==============
// fill depends on scans; GEMM-0 depends only on k_prep -> independent, co-run.
// blocks [0,784): fill (bucket = blockIdx&7); [784,1566): node GEMM; [1566,2348): edge GEMM
#define FILL_SEGS 98
#define FILL_PER  8164
#define FILL_BLKS (FILL_SEGS * 8)
__global__ void __launch_bounds__(256)
k_fill_gemm0(const int* __restrict__ ei, const int* __restrict__ off_n,
             const int* __restrict__ off_h, int* __restrict__ cur_n,
             int* __restrict__ cur_h, int* __restrict__ adj_n,
             int* __restrict__ adj_h,
             const float* __restrict__ Xn, const __half* __restrict__ Wtn,
             __half* __restrict__ Yn,
             const float* __restrict__ Xe, const __half* __restrict__ Wte,
             __half* __restrict__ Ye) {
    __shared__ __align__(16) __half smem[(64 + 128) * 56];
    int b = blockIdx.x;
    if (b < FILL_BLKS) {
        int bucket = b & 7;
        int seg = b >> 3;
        int lo = seg * FILL_PER;
        int hi = min(lo + FILL_PER, NI);
        for (int e = lo + (int)threadIdx.x; e < hi; e += 256) {
            int s = ei[e], d = ei[e + NI];
            if (d / 6250 == bucket) {
                int p = atomicAdd(&cur_h[d], 1);
                adj_h[off_h[d] + p] = s;
            }
            if (s / 6250 == bucket) {
                int q = atomicAdd(&cur_n[s], 1);
                adj_n[off_n[s] + q] = d;
            }
        }
    } else if (b < FILL_BLKS + 782) {
        gemm_body<float, 64, 128, 4, 2>(Xn, Wtn, Yn, NN, 256, b - FILL_BLKS, smem);
    } else {
        gemm_body<float, 64, 64, 4, 1>(Xe, Wte, Ye, NH, 128, b - FILL_BLKS - 782, smem);
    }
}

// layers 1-2 GEMM (fp16 inputs): blocks [0,782) node, rest edge
__global__ void __launch_bounds__(256)
k_gemm2(const __half* __restrict__ Xn, const __half* __restrict__ Wtn,
        __half* __restrict__ Yn, int Kn,
        const __half* __restrict__ Xe, const __half* __restrict__ Wte,
        __half* __restrict__ Ye, int Ke) {
    __shared__ __align__(16) __half smem[(64 + 128) * 56];
    if (blockIdx.x < 782)
        gemm_body<__half, 64, 128, 4, 2>(Xn, Wtn, Yn, NN, Kn, blockIdx.x, smem);
    else
        gemm_body<__half, 64, 64, 4, 1>(Xe, Wte, Ye, NH, Ke, blockIdx.x - 782, smem);
}

// ================= pull body: 16B gathers, 8-way unrolled ========
template <int F, bool RELU>
static __device__ __forceinline__ void pull_body(const __half* __restrict__ in,
                                                 const int* __restrict__ off,
                                                 const int* __restrict__ adj,
                                                 const float* __restrict__ scale,
                                                 const float* __restrict__ bias,
                                                 __half* __restrict__ out,
                                                 int nrows, int blk) {
    constexpr int TPR = F / 8;
    constexpr int RPB = 256 / TPR;
    int r = blk * RPB + (int)threadIdx.x / TPR;
    int lane = threadIdx.x % TPR;
    if (r >= nrows) return;
    int lo = off[r], hi = off[r + 1];
    const float4* in4 = (const float4*)in;
    float4 a0 = {0,0,0,0}, b0 = {0,0,0,0}, a1 = {0,0,0,0}, b1v = {0,0,0,0};
    float4 a2 = {0,0,0,0}, b2v = {0,0,0,0}, a3 = {0,0,0,0}, b3 = {0,0,0,0};
    int j = lo;
    for (; j + 7 < hi; j += 8) {
        int c0 = adj[j], c1 = adj[j + 1], c2 = adj[j + 2], c3 = adj[j + 3];
        int c4 = adj[j + 4], c5 = adj[j + 5], c6 = adj[j + 6], c7 = adj[j + 7];
        float4 v0 = in4[(size_t)c0 * TPR + lane];
        float4 v1 = in4[(size_t)c1 * TPR + lane];
        float4 v2 = in4[(size_t)c2 * TPR + lane];
        float4 v3 = in4[(size_t)c3 * TPR + lane];
        float4 v4 = in4[(size_t)c4 * TPR + lane];
        float4 v5 = in4[(size_t)c5 * TPR + lane];
        float4 v6 = in4[(size_t)c6 * TPR + lane];
        float4 v7 = in4[(size_t)c7 * TPR + lane];
        acc_h8(a0, b0, v0); acc_h8(a1, b1v, v1); acc_h8(a2, b2v, v2); acc_h8(a3, b3, v3);
        acc_h8(a0, b0, v4); acc_h8(a1, b1v, v5); acc_h8(a2, b2v, v6); acc_h8(a3, b3, v7);
    }
    for (; j + 1 < hi; j += 2) {
        int c0 = adj[j], c1 = adj[j + 1];
        float4 v0 = in4[(size_t)c0 * TPR + lane];
        float4 v1 = in4[(size_t)c1 * TPR + lane];
        acc_h8(a0, b0, v0); acc_h8(a1, b1v, v1);
    }
    if (j < hi) {
        float4 v0 = in4[(size_t)adj[j] * TPR + lane];
        acc_h8(a0, b0, v0);
    }
    a0.x += a1.x + a2.x + a3.x; a0.y += a1.y + a2.y + a3.y;
    a0.z += a1.z + a2.z + a3.z; a0.w += a1.w + a2.w + a3.w;
    b0.x += b1v.x + b2v.x + b3.x; b0.y += b1v.y + b2v.y + b3.y;
    b0.z += b1v.z + b2v.z + b3.z; b0.w += b1v.w + b2v.w + b3.w;
    float sc = scale[r];
    if (RELU) {
        float4 ba = ((const float4*)bias)[lane * 2];
        float4 bb = ((const float4*)bias)[lane * 2 + 1];
        a0.x = fmaxf(fmaf(a0.x, sc, ba.x), 0.f);
        a0.y = fmaxf(fmaf(a0.y, sc, ba.y), 0.f);
        a0.z = fmaxf(fmaf(a0.z, sc, ba.z), 0.f);
        a0.w = fmaxf(fmaf(a0.w, sc, ba.w), 0.f);
        b0.x = fmaxf(fmaf(b0.x, sc, bb.x), 0.f);
        b0.y = fmaxf(fmaf(b0.y, sc, bb.y), 0.f);
        b0.z = fmaxf(fmaf(b0.z, sc, bb.z), 0.f);
        b0.w = fmaxf(fmaf(b0.w, sc, bb.w), 0.f);
    } else {
        a0.x *= sc; a0.y *= sc; a0.z *= sc; a0.w *= sc;
        b0.x *= sc; b0.y *= sc; b0.z *= sc; b0.w *= sc;
    }
    ((float4*)out)[(size_t)r * TPR + lane] = pack_h8(a0, b0);
}

// combined pull: blocks [0,3125) = F=128 side, [3125,4688) = F=64 side
template <bool RELU>
__global__ void k_pull2(const __half* __restrict__ inA, const int* __restrict__ offA,
                        const int* __restrict__ adjA, const float* __restrict__ scA,
                        const float* __restrict__ biA, __half* __restrict__ outA, int rowsA,
                        const __half* __restrict__ inB, const int* __restrict__ offB,
                        const int* __restrict__ adjB, const float* __restrict__ scB,
                        const float* __restrict__ biB, __half* __restrict__ outB, int rowsB) {
    if (blockIdx.x < 3125)
        pull_body<128, RELU>(inA, offA, adjA, scA, biA, outA, rowsA, blockIdx.x);
    else
        pull_body<64, RELU>(inB, offB, adjB, scB, biB, outB, rowsB, blockIdx.x - 3125);
}

// ================= fused final MLP via MFMA ==================================
__global__ void __launch_bounds__(256)
k_mlp_mfma(const __half* __restrict__ hx1, const __half* __restrict__ hx2,
           const __half* __restrict__ hx3, const __half* __restrict__ gx1,
           const __half* __restrict__ gx2, const __half* __restrict__ gx3,
           const int* __restrict__ marks, const int* __restrict__ emarks,
           const __half* __restrict__ W1t, const float* __restrict__ b1,
           const float* __restrict__ W2, const float* __restrict__ b2,
           float* __restrict__ out) {
    constexpr int LDK = 56;
    __shared__ __align__(16) __half Xs[32 * LDK];
    __shared__ __align__(16) __half Ws[256 * LDK];
    __shared__ float part[4][32][2];
    int t = threadIdx.x;
    int wave = t >> 6, lane = t & 63;
    int g = lane >> 4, lr = lane & 15;
    int bm0 = blockIdx.x * 32;
    int r_s = t >> 2, q_s = t & 3;
    int m_s = 0, e_s = 0;
    if (t < 128) {
        int l = bm0 + r_s; if (l >= NL) l = NL - 1;
        m_s = marks[l]; e_s = emarks[l];
    }
    f32x4 acc[2][4] = {};

    for (int k0 = 0; k0 < 768; k0 += 32) {
        if (t < 128) {
            if (k0 < 384) {
                int fb = (k0 < 192 ? k0 : k0 - 192) + q_s * 8;
                const __half* gs = fb < 64 ? gx1 : (fb < 128 ? gx2 : gx3);
                int off = fb & 63;
                half8 va = *(const half8*)&gs[(size_t)e_s * 64 + off];
                half8 vb = *(const half8*)&gs[(size_t)(e_s + 1) * 64 + off];
                half8 rv;
                if (k0 < 192) {
#pragma unroll
                    for (int j = 0; j < 8; j++)
                        rv[j] = (_Float16)fminf((float)va[j], (float)vb[j]);
                } else {
#pragma unroll
                    for (int j = 0; j < 8; j++)
                        rv[j] = (_Float16)fmaxf((float)va[j], (float)vb[j]);
                }
                *(half8*)&Xs[r_s * LDK + q_s * 8] = rv;
            } else {
                int fb = (k0 - 384) + q_s * 8;
                const __half* hs = fb < 128 ? hx1 : (fb < 256 ? hx2 : hx3);
                int off = fb & 127;
                *(float4*)&Xs[r_s * LDK + q_s * 8] = *(const float4*)&hs[(size_t)m_s * 128 + off];
            }
        }
        for (int u = t; u < 1024; u += 256) {
            int r = u >> 2, q = u & 3;
            *(float4*)&Ws[r * LDK + q * 8] = *(const float4*)&W1t[(size_t)r * 768 + k0 + q * 8];
        }
        __syncthreads();
        half8 a[2], b[4];
#pragma unroll
        for (int fm = 0; fm < 2; fm++)
            a[fm] = *(const half8*)&Xs[(fm * 16 + lr) * LDK + g * 8];
#pragma unroll
        for (int fn = 0; fn < 4; fn++)
            b[fn] = *(const half8*)&Ws[(wave * 64 + fn * 16 + lr) * LDK + g * 8];
#pragma unroll
        for (int fm = 0; fm < 2; fm++)
#pragma unroll
            for (int fn = 0; fn < 4; fn++)
                acc[fm][fn] = __builtin_amdgcn_mfma_f32_16x16x32_f16(a[fm], b[fn], acc[fm][fn], 0, 0, 0);
        __syncthreads();
    }
    float b1c[4], w20[4], w21[4];
#pragma unroll
    for (int fn = 0; fn < 4; fn++) {
        int col = wave * 64 + fn * 16 + lr;
        b1c[fn] = b1[col];
        w20[fn] = W2[(size_t)col * 2 + 0];
        w21[fn] = W2[(size_t)col * 2 + 1];
    }
    float p0[2][4], p1[2][4];
#pragma unroll
    for (int fm = 0; fm < 2; fm++) {
#pragma unroll
        for (int reg = 0; reg < 4; reg++) {
            float s0 = 0.f, s1 = 0.f;
#pragma unroll
            for (int fn = 0; fn < 4; fn++) {
                float hh = fmaxf(acc[fm][fn][reg] + b1c[fn], 0.f);
                s0 = fmaf(hh, w20[fn], s0);
                s1 = fmaf(hh, w21[fn], s1);
            }
            p0[fm][reg] = s0; p1[fm][reg] = s1;
        }
    }
#pragma unroll
    for (int mask = 1; mask < 16; mask <<= 1) {
#pragma unroll
        for (int fm = 0; fm < 2; fm++)
#pragma unroll
            for (int reg = 0; reg < 4; reg++) {
                p0[fm][reg] += __shfl_xor(p0[fm][reg], mask);
                p1[fm][reg] += __shfl_xor(p1[fm][reg], mask);
            }
    }
    if (lr == 0) {
#pragma unroll
        for (int fm = 0; fm < 2; fm++)
#pragma unroll
            for (int reg = 0; reg < 4; reg++) {
                int row = fm * 16 + g * 4 + reg;
                part[wave][row][0] = p0[fm][reg];
                part[wave][row][1] = p1[fm][reg];
            }
    }
    __syncthreads();
    if (t < 32) {
        int l = bm0 + t;
        if (l < NL) {
            float l0 = part[0][t][0] + part[1][t][0] + part[2][t][0] + part[3][t][0] + b2[0];
            float l1 = part[0][t][1] + part[1][t][1] + part[2][t][1] + part[3][t][1] + b2[1];
            float mx = fmaxf(l0, l1);
            float lse = mx + logf(expf(l0 - mx) + expf(l1 - mx));
            out[(size_t)l * 2 + 0] = l0 - lse;
            out[(size_t)l * 2 + 1] = l1 - lse;
        }
    }
}

extern "C" void kernel_launch(void* const* d_in, const int* in_sizes, int n_in,
                              void* d_out, int out_size, void* d_ws, size_t ws_size,
                              hipStream_t stream) {
    const float* x      = (const float*)d_in[0];
    const float* ex     = (const float*)d_in[1];
    const int*   ei     = (const int*)d_in[2];
    const int*   marks  = (const int*)d_in[3];
    const int*   emarks = (const int*)d_in[4];
    const float* Wn[3] = {(const float*)d_in[5],  (const float*)d_in[9],  (const float*)d_in[13]};
    const float* bn[3] = {(const float*)d_in[6],  (const float*)d_in[10], (const float*)d_in[14]};
    const float* We[3] = {(const float*)d_in[7],  (const float*)d_in[11], (const float*)d_in[15]};
    const float* be[3] = {(const float*)d_in[8],  (const float*)d_in[12], (const float*)d_in[16]};
    const float* W1 = (const float*)d_in[17];
    const float* b1 = (const float*)d_in[18];
    const float* W2 = (const float*)d_in[19];
    const float* b2 = (const float*)d_in[20];

    // ---- workspace layout ----
    int*    off_n = (int*)d_ws;                // 50004
    int*    off_h = off_n + 50004;             // 50004
    int*    adj_n = off_h + 50004;             // 800000
    int*    adj_h = adj_n + 800000;            // 800000
    int*    cnt   = adj_h + 800000;            // 100000
    int*    cur   = cnt + 100000;              // 100000
    int*    parts = cur + 100000;              // 512
    float*  invn  = (float*)(parts + 512);     // 50000
    float*  invh  = invn + 50000;              // 50000
    __half* xwb   = (__half*)(invh + 50000);   // 6.4M
    __half* xwb2  = xwb + 6400000;             // 3.2M
    __half* heb   = xwb2 + 3200000;            // 6.4M
    __half* heb2  = heb + 6400000;             // 3.2M
    __half* h[3]  = {heb2 + 3200000, heb2 + 9600000, heb2 + 16000000};  // 6.4M each
    __half* g[3]  = {h[2] + 6400000, h[2] + 9600000, h[2] + 12800000};  // 3.2M each
    __half* Wnt[3] = {g[2] + 3200000, g[2] + 3232768, g[2] + 3249152};
    __half* Wet[3] = {g[2] + 3265536, g[2] + 3273728, g[2] + 3277824};
    __half* W1t    = g[2] + 3281920;

    int* cnt_n = cnt;
    int* cnt_h = cnt + 50000;
    int* cur_n = cur;
    int* cur_h = cur + 50000;

    // ---- prep + CSR build ----
    hipMemsetAsync(cnt, 0, 200000 * sizeof(int), stream);   // counts + cursors
    k_prep<<<WT_BLKS + HIST_SEGS * 8, 256, 0, stream>>>(
        Wn[0], Wn[1], Wn[2], We[0], We[1], We[2], W1,
        Wnt[0], Wnt[1], Wnt[2], Wet[0], Wet[1], Wet[2], W1t,
        ei, cnt_n, cnt_h);
    k_scanp1<<<392, 256, 0, stream>>>(cnt_n, cnt_h, parts);
    k_scanp2<<<2, 256, 0, stream>>>(parts, off_n, off_h);
    k_scanp3<<<392, 256, 0, stream>>>(cnt_n, cnt_h, parts, off_n, off_h, invn, invh);

    // ---- merged CSR fill + layer-0 GEMMs (independent work, one launch) ----
    k_fill_gemm0<<<FILL_BLKS + 1564, 256, 0, stream>>>(
        ei, off_n, off_h, cur_n, cur_h, adj_n, adj_h,
        x, Wnt[0], xwb, ex, Wet[0], xwb2);

    // ---- conv chains ----
    k_pull2<false><<<4688, 256, 0, stream>>>(xwb, off_h, adj_h, invh, nullptr, heb, NH,
                                             xwb2, off_n, adj_n, invn, nullptr, heb2, NN);
    k_pull2<true><<<4688, 256, 0, stream>>>(heb, off_n, adj_n, invn, bn[0], h[0], NN,
                                            heb2, off_h, adj_h, invh, be[0], g[0], NH);
    for (int i = 1; i < 3; i++) {
        k_gemm2<<<1564, 256, 0, stream>>>(h[i - 1], Wnt[i], xwb, 128,
                                          g[i - 1], Wet[i], xwb2, 64);
        k_pull2<false><<<4688, 256, 0, stream>>>(xwb, off_h, adj_h, invh, nullptr, heb, NH,
                                                 xwb2, off_n, adj_n, invn, nullptr, heb2, NN);
        k_pull2<true><<<4688, 256, 0, stream>>>(heb, off_n, adj_n, invn, bn[i], h[i], NN,
                                                heb2, off_h, adj_h, invh, be[i], g[i], NH);
    }

    // ---- fused final MLP (MFMA) + head + log_softmax ----
    k_mlp_mfma<<<(NL + 31) / 32, 256, 0, stream>>>(h[0], h[1], h[2], g[0], g[1], g[2],
                                                   marks, emarks, W1t, b1, W2, b2, (float*)d_out);
}